// Round 7
// baseline (543.862 us; speedup 1.0000x reference)
//
#include <hip/hip_runtime.h>
#include <math.h>

#define BN 16
#define NA 16384   // anchors per image (128*128)
#define NG 60
#define NC 80
#define ND 85
#define SLABS 16   // slabs per image
#define SLAB 1024  // anchors per slab
#define TILE 128   // anchors per LDS tile
#define NTILES 8   // SLAB/TILE
#define GSLOT 64   // padded gt slots

typedef unsigned long long u64;
#define PK_EMPTY 0xFFFFFFFFFFFFFFFFull

__device__ __forceinline__ float softplus_fast(float x){
  // softplus(x) = max(x,0) + log1p(exp(-|x|)); u=exp(-|x|) >= 6.7e-3 for |x|<=5,
  // so log(1+u) via v_log is accurate to ~1e-7 abs — far inside the 5.3 threshold.
  return __logf(1.0f + __expf(-fabsf(x))) + fmaxf(x, 0.0f);
}

// pack (cost,idx): cost >= -3e-8 analytically (softplus(x)-x >= 0), so after
// fmaxf(cost,0) the float bit pattern is order-preserving; idx in low 32 bits
// reproduces the reference's stable (ascending-index) tie-break under u64 <.
__device__ __forceinline__ u64 pack_ci(float cost, int idx){
  return ((u64)__float_as_uint(fmaxf(cost, 0.0f)) << 32) | (unsigned)idx;
}

// ---------------- F1: fused prep + per-(image,gt) scan ----------------
// grid = 256 (b = blk>>4, slab = blk&15), block = 1024 (16 waves)
// thread t: g = t>>4 (64 gt slots, 60 real), strip = t&15; scans 64 anchors.
__global__ __launch_bounds__(1024) void f_scan(
    const float* __restrict__ preds, const float* __restrict__ gt_boxes,
    const int* __restrict__ gt_labels, float* __restrict__ mlist)
{
  __shared__ float4 tilev[TILE*ND/4];   // 128 rows x 85 floats = 43520 B
  __shared__ float sp[TILE];
  __shared__ float pav[TILE];
  __shared__ float4 gtb4[GSLOT];
  __shared__ float gar[GSLOT];
  __shared__ int   lab[GSLOT];
  float* tile = (float*)tilev;
  const int t = threadIdx.x;
  const int b = blockIdx.x >> 4;
  const int slab = blockIdx.x & 15;

  if (t < GSLOT){
    float4 gg = make_float4(0.f,0.f,0.f,0.f);
    int lb = 0;
    if (t < NG){ gg = ((const float4*)gt_boxes)[b*NG + t]; lb = gt_labels[b*NG + t]; }
    gtb4[t] = gg; lab[t] = lb;
    gar[t] = fmaxf(gg.z-gg.x,0.f)*fmaxf(gg.w-gg.y,0.f);
  }
  __syncthreads();
  const int g = t >> 4, strip = t & 15;
  const float4 gt = gtb4[g];
  const float ga = gar[g];
  const int lg = lab[g];

  float il[10];            // top-10 ious (desc)
  u64   pk[10];            // bottom-10 packed (cost,idx) (asc)
  #pragma unroll
  for (int j=0;j<10;j++){ il[j] = -1.f; pk[j] = PK_EMPTY; }

  const float4* src0 = (const float4*)(preds + ((size_t)b*3*NA + (size_t)slab*SLAB)*ND);

  for (int ti = 0; ti < NTILES; ti++){
    __syncthreads();                       // protect tile/sp from previous iter readers
    const float4* src = src0 + (size_t)ti*(TILE*ND/4);
    #pragma unroll
    for (int i = 0; i < 3; i++){
      int idx = t + i*1024;
      if (idx < TILE*ND/4) tilev[idx] = src[idx];
    }
    __syncthreads();
    // spsum + box area: 8 threads per anchor, 10 softplus each, shfl-tree combine
    {
      int a = t >> 3, part = t & 7;
      const float* rowc = tile + a*ND + 5 + part*10;
      float p = 0.f;
      #pragma unroll
      for (int c = 0; c < 10; c++) p += softplus_fast(rowc[c]);
      p += __shfl_xor(p, 1);
      p += __shfl_xor(p, 2);
      p += __shfl_xor(p, 4);
      if (part == 0) sp[a] = p;
      if (part == 1){
        const float* row = tile + a*ND;
        pav[a] = fmaxf(row[2]-row[0],0.f)*fmaxf(row[3]-row[1],0.f);
      }
    }
    __syncthreads();
    const int n0 = slab*SLAB + ti*TILE;
    for (int r = 0; r < 8; r++){
      int a = (r<<4) + strip;
      const float* row = tile + a*ND;
      float bx1=row[0], by1=row[1], bx2=row[2], by2=row[3];
      float clsv = row[5+lg];
      float spv  = sp[a];
      float pa   = pav[a];
      float ix = fmaxf(fminf(gt.z,bx2)-fmaxf(gt.x,bx1), 0.f);
      float iy = fmaxf(fminf(gt.w,by2)-fmaxf(gt.y,by1), 0.f);
      float inter = ix*iy;
      float iou = __fdividef(inter, ga + pa - inter + 1e-8f);
      float cost = fmaf(-3.0f, __logf(iou + 1e-8f), spv - clsv);
      u64 key = pack_ci(cost, n0 + a);
      if (__any(iou > il[9])){            // ious are mostly 0 on this data -> skips
        float v = iou;
        #pragma unroll
        for (int j=0;j<10;j++){ bool c = v > il[j]; float o=il[j]; il[j]=c?v:o; v=c?o:v; }
      }
      if (__any(key < pk[9])){            // strict <, ascending-idx scan => stable
        u64 kv = key;
        #pragma unroll
        for (int j=0;j<10;j++){ bool c = kv < pk[j]; u64 o=pk[j]; pk[j]=c?kv:o; kv=c?o:kv; }
      }
    }
  }

  // merge 16 strips per g (16-lane butterflies), write slab-level lists
  float* outp = mlist + (((size_t)(b*SLABS + slab))*NG + g)*30;  // 10 f32 + 10 u64
  u64* outpk = (u64*)(outp + 10);
  for (int r = 0; r < 10; r++){           // top-10 iou values (who-tiebreak: pop exactly one)
    float v = il[0]; int who = strip;
    #pragma unroll
    for (int off = 8; off; off >>= 1){
      float ov = __shfl_xor(v, off, 16);
      int   ow = __shfl_xor(who, off, 16);
      if (ov > v || (ov == v && ow < who)){ v = ov; who = ow; }
    }
    if (strip == r && g < NG) outp[r] = v;
    if (strip == who){
      #pragma unroll
      for (int j=0;j<9;j++) il[j] = il[j+1];
      il[9] = -1.f;
    }
  }
  for (int r = 0; r < 10; r++){           // bottom-10 packed (unique keys)
    u64 v = pk[0];
    #pragma unroll
    for (int off = 8; off; off >>= 1){
      u64 ov = __shfl_xor(v, off, 16);
      if (ov < v) v = ov;
    }
    if (strip == r && g < NG) outpk[r] = v;
    if (pk[0] == v){                      // exactly one strip (keys unique)
      #pragma unroll
      for (int j=0;j<9;j++) pk[j] = pk[j+1];
      pk[9] = PK_EMPTY;
    }
  }
}

// ---------------- F2: cross-slab merge + dynamic-k selection ----------------
// grid = 960 (bid = b*60+g), block = 64 (one wave)
__global__ __launch_bounds__(64) void f_merge(const float* __restrict__ mlist,
    int* __restrict__ matched, int* __restrict__ cnt)
{
  __shared__ float bufio[SLABS*10];
  __shared__ u64   bufpk[SLABS*10];
  const int bid = blockIdx.x;
  const int b = bid / NG, g = bid - b*NG;
  const int t = threadIdx.x;
  for (int i = t; i < SLABS*10; i += 64){
    int slab = i / 10, j = i - slab*10;
    const float* entry = mlist + (((size_t)(b*SLABS + slab))*NG + g)*30;
    bufio[i] = entry[j];
    bufpk[i] = ((const u64*)(entry + 10))[j];
  }
  __syncthreads();

  // --- top-10 of 160 iou values (3 items/lane) ---
  float v0 = bufio[t], v1 = bufio[t+64], v2 = (t < 32) ? bufio[t+128] : -1.f;
  if (v1 > v0){ float x=v0; v0=v1; v1=x; }
  if (v2 > v1){ float x=v1; v1=v2; v2=x; }
  if (v1 > v0){ float x=v0; v0=v1; v1=x; }
  float s10 = 0.f;
  for (int r = 0; r < 10; r++){
    float v = v0; int who = t;
    #pragma unroll
    for (int off = 32; off; off >>= 1){
      float ov = __shfl_xor(v, off);
      int   ow = __shfl_xor(who, off);
      if (ov > v || (ov == v && ow < who)){ v = ov; who = ow; }
    }
    s10 += v;
    if (t == who){ v0=v1; v1=v2; v2=-1.f; }
  }
  const int k = (int)fmaxf(s10, 1.0f);    // truncation matches astype(int32)

  // --- k smallest of 160 packed (cost,idx); keys unique among reals ---
  u64 c0 = bufpk[t], c1 = bufpk[t+64], c2 = (t < 32) ? bufpk[t+128] : PK_EMPTY;
  if (c1 < c0){ u64 x=c0; c0=c1; c1=x; }
  if (c2 < c1){ u64 x=c1; c1=c2; c2=x; }
  if (c1 < c0){ u64 x=c0; c0=c1; c1=x; }
  for (int r = 0; r < k; r++){
    u64 v = c0; int who = t;
    #pragma unroll
    for (int off = 32; off; off >>= 1){
      u64 ov = __shfl_xor(v, off);
      int ow = __shfl_xor(who, off);
      if (ov < v || (ov == v && ow < who)){ v = ov; who = ow; }
    }
    if (t == r) matched[bid*10 + r] = (int)(unsigned)(v & 0xFFFFFFFFull);
    if (t == who){ c0=c1; c1=c2; c2=PK_EMPTY; }
  }
  if (t == 0) cnt[bid] = k;
}

// ---------------- F3: per-image loss over candidate anchors ----------------
__device__ __forceinline__ float blockSum(float v, float* red, int t){
  red[t] = v; __syncthreads();
  #pragma unroll
  for (int s = 128; s > 0; s >>= 1){
    if (t < s) red[t] += red[t+s];
    __syncthreads();
  }
  float r = red[0]; __syncthreads();
  return r;
}

__global__ __launch_bounds__(256) void f_loss(const float* __restrict__ preds,
    const float* __restrict__ gt_boxes, const int* __restrict__ gt_labels,
    const int* __restrict__ matched, const int* __restrict__ cnt,
    float* __restrict__ partials)
{
  __shared__ int lists[NG*10];
  __shared__ int cnts[NG];
  __shared__ float gtb[NG][4];
  __shared__ int labs[NG];
  __shared__ float red[256];
  const int b = blockIdx.x;
  const int t = threadIdx.x;
  for (int i = t; i < NG*10; i += 256) lists[i] = matched[b*NG*10 + i];
  if (t < NG){
    cnts[t] = cnt[b*NG + t];
    float4 gg = ((const float4*)gt_boxes)[b*NG + t];
    gtb[t][0]=gg.x; gtb[t][1]=gg.y; gtb[t][2]=gg.z; gtb[t][3]=gg.w;
    labs[t] = gt_labels[b*NG + t];
  }
  __syncthreads();
  for (int i = t; i < NG*10; i += 256){
    int g = i/10, j = i - g*10;
    if (j >= cnts[g]) lists[i] = -1;
  }
  __syncthreads();

  float boxs = 0.f, objs = 0.f, clss = 0.f, nfg = 0.f;
  const float* rowb = preds + (size_t)b*3*NA*ND;
  for (int s = t; s < NG*10; s += 256){
    int n = lists[s];
    if (n < 0) continue;
    int g = s/10;
    int m = 0, firstg = -1;
    for (int gp = 0; gp < NG; gp++){
      bool mem = false;
      #pragma unroll
      for (int jp = 0; jp < 10; jp++) mem |= (lists[gp*10 + jp] == n);
      if (mem){ m++; if (firstg < 0) firstg = gp; }
    }
    if (g != firstg) continue;        // unique owner slot per anchor
    const float* row = rowb + (size_t)n*ND;
    float p0=row[0], p1=row[1], p2=row[2], p3=row[3];
    float obj = row[4];
    float spv = 0.f;
    for (int c = 0; c < NC; c++) spv += softplus_fast(row[5+c]);
    int mg = g;
    float pa = fmaxf(p2-p0,0.f)*fmaxf(p3-p1,0.f);
    if (m > 1){
      float best = INFINITY; int bg = 0;
      for (int gp = 0; gp < NG; gp++){
        float ga = fmaxf(gtb[gp][2]-gtb[gp][0],0.f)*fmaxf(gtb[gp][3]-gtb[gp][1],0.f);
        float ix = fmaxf(fminf(gtb[gp][2],p2)-fmaxf(gtb[gp][0],p0),0.f);
        float iy = fmaxf(fminf(gtb[gp][3],p3)-fmaxf(gtb[gp][1],p1),0.f);
        float inter = ix*iy;
        float iou = __fdividef(inter, ga + pa - inter + 1e-8f);
        float c = fmaf(-3.0f, __logf(iou + 1e-8f), spv - row[5+labs[gp]]);
        if (c < best){ best = c; bg = gp; }
      }
      bool mem = false;
      #pragma unroll
      for (int jp = 0; jp < 10; jp++) mem |= (lists[bg*10 + jp] == n);
      if (!mem) continue;             // multi & best not in matched set -> not fg
      mg = bg;
    }
    float gx1=gtb[mg][0], gy1=gtb[mg][1], gx2=gtb[mg][2], gy2=gtb[mg][3];
    float d0=p0-gx1, d1=p1-gy1, d2=p2-gx2, d3=p3-gy2;
    float q0=fabsf(d0), q1=fabsf(d1), q2=fabsf(d2), q3=fabsf(d3);
    float sl = (q0<1.f ? 0.5f*d0*d0 : q0-0.5f)
             + (q1<1.f ? 0.5f*d1*d1 : q1-0.5f)
             + (q2<1.f ? 0.5f*d2*d2 : q2-0.5f)
             + (q3<1.f ? 0.5f*d3*d3 : q3-0.5f);
    float ga = fmaxf(gx2-gx1,0.f)*fmaxf(gy2-gy1,0.f);
    float ix = fmaxf(fminf(gx2,p2)-fmaxf(gx1,p0),0.f);
    float iy = fmaxf(fminf(gy2,p3)-fmaxf(gy1,p1),0.f);
    float inter = ix*iy;
    float iou_t = inter/(pa + ga - inter + 1e-8f);
    float sg = 1.f/(1.f + __expf(-obj));
    float obce = softplus_fast(sg) - sg*iou_t;
    float clsb = spv - row[5+labs[mg]];
    boxs += sl; objs += obce; clss += clsb; nfg += 1.f;
  }
  float tb = blockSum(boxs, red, t);
  float to = blockSum(objs, red, t);
  float tc = blockSum(clss, red, t);
  float tn = blockSum(nfg,  red, t);
  if (t == 0){
    partials[b*4+0] = tb; partials[b*4+1] = to;
    partials[b*4+2] = tc; partials[b*4+3] = tn;
  }
}

// ---------------- F4: final combine ----------------
__global__ void f_final(const float* __restrict__ partials, float* __restrict__ out){
  if (threadIdx.x == 0 && blockIdx.x == 0){
    float tb=0.f, to=0.f, tc=0.f;
    for (int b = 0; b < BN; b++){
      float nf = fmaxf(partials[b*4+3], 1.f);
      tb += partials[b*4+0] / (nf * 4.f);
      to += partials[b*4+1] / nf;
      tc += partials[b*4+2] / (nf * (float)NC);
    }
    out[0] = (5.f*tb + to + tc) / (float)BN;
    out[1] = tb / (float)BN;
    out[2] = to / (float)BN;
    out[3] = tc / (float)BN;
  }
}

extern "C" void kernel_launch(void* const* d_in, const int* in_sizes, int n_in,
                              void* d_out, int out_size, void* d_ws, size_t ws_size,
                              hipStream_t stream)
{
  (void)in_sizes; (void)n_in; (void)out_size; (void)ws_size;
  const float* preds     = (const float*)d_in[0];
  const float* gt_boxes  = (const float*)d_in[1];
  const int*   gt_labels = (const int*)d_in[2];
  float* out = (float*)d_out;

  float* mlist  = (float*)d_ws;                       // 16*16*60*30 words (1.84 MB)
  int* matched  = (int*)(mlist + (size_t)BN*SLABS*NG*30); // 16*60*10
  int* cnt      = matched + BN*NG*10;                 // 16*60
  float* partials = (float*)(cnt + BN*NG);            // 16*4

  f_scan <<<BN*SLABS, 1024, 0, stream>>>(preds, gt_boxes, gt_labels, mlist);
  f_merge<<<BN*NG,      64, 0, stream>>>(mlist, matched, cnt);
  f_loss <<<BN,        256, 0, stream>>>(preds, gt_boxes, gt_labels, matched, cnt, partials);
  f_final<<<1,          64, 0, stream>>>(partials, out);
}